// Round 1
// baseline (495.734 us; speedup 1.0000x reference)
//
#include <hip/hip_runtime.h>

// Problem constants
#define N_NODES 4096
#define C_IN    256
#define HID     256
#define BATCH   8
#define R_TOT   32768   // BATCH * N_NODES

typedef unsigned short u16;
typedef short s8v  __attribute__((ext_vector_type(8)));   // 8 bf16 (bit pattern in shorts)
typedef float f4v  __attribute__((ext_vector_type(4)));
typedef u16   u16x4 __attribute__((ext_vector_type(4)));

#define MFMA(a,b,c) __builtin_amdgcn_mfma_f32_16x16x32_bf16((a),(b),(c),0,0,0)

__device__ __forceinline__ u16 bf_rne(float x) {
    unsigned u = __float_as_uint(x);
    u += 0x7fffu + ((u >> 16) & 1u);
    return (u16)(u >> 16);
}
__device__ __forceinline__ float bf_f(u16 h) {
    return __uint_as_float(((unsigned)h) << 16);
}
// fp32 -> bf16 hi/lo split: x ~= hi + lo, |err| <= 2^-18 |x|
__device__ __forceinline__ void split2f(float x, u16& h, u16& l) {
    h = bf_rne(x);
    l = bf_rne(x - bf_f(h));
}

// async global->LDS, 16B per lane. lds ptr must be wave-uniform (dest = base + lane*16)
__device__ __forceinline__ void glds16(const void* g, void* l) {
    __builtin_amdgcn_global_load_lds(
        (const __attribute__((address_space(1))) void*)g,
        (__attribute__((address_space(3))) void*)l, 16, 0, 0);
}

// ---------------- split kernels ----------------

// elementwise fp32 -> (hi,lo) bf16, float4-vectorized
__global__ void splitK_k(const float* __restrict__ in, u16* __restrict__ oh,
                         u16* __restrict__ ol, int n4) {
    int i = blockIdx.x * blockDim.x + threadIdx.x;
    int stride = gridDim.x * blockDim.x;
    for (; i < n4; i += stride) {
        float4 x = ((const float4*)in)[i];
        u16x4 hh, ll; u16 a, b;
        split2f(x.x, a, b); hh[0] = a; ll[0] = b;
        split2f(x.y, a, b); hh[1] = a; ll[1] = b;
        split2f(x.z, a, b); hh[2] = a; ll[2] = b;
        split2f(x.w, a, b); hh[3] = a; ll[3] = b;
        ((u16x4*)oh)[i] = hh; ((u16x4*)ol)[i] = ll;
    }
}

// transpose + split for the 256x256 weight matrices: out[h][c] = in[c][h]
__global__ void splitT_k(const float* __restrict__ in, u16* __restrict__ oh,
                         u16* __restrict__ ol) {
    int c = blockIdx.x;      // row of in
    int h = threadIdx.x;     // col of in
    float v = in[c * 256 + h];
    u16 hi, lo; split2f(v, hi, lo);
    oh[h * 256 + c] = hi;
    ol[h * 256 + c] = lo;
}

// ---------------- small GEMM: T[i=hid'][j=r] = sum_k Wt[i][k] * Bf[j][k] + bias[i] ----------------
// A (Wt) pre-split bf16 [256][256]; B fp32 [32768][256] reg-staged+split on the fly.
// Output written split hi/lo, transposed layout [256][32768]. No relu.
__global__ __launch_bounds__(256, 2) void gemm_small_k(
    const u16* __restrict__ Ah, const u16* __restrict__ Al,
    const float* __restrict__ Bf, const float* __restrict__ bias,
    u16* __restrict__ Oh, u16* __restrict__ Ol)
{
    __shared__ u16 sAh[4096], sAl[4096], sBh[4096], sBl[4096];  // 128x32 each
    const int tid = threadIdx.x;
    const int w = tid >> 6, lane = tid & 63;
    const int i0 = blockIdx.x * 128;   // output row tile (hid')
    const int r0 = blockIdx.y * 128;   // output col tile (r)
    const int lr = lane & 15, lk = lane >> 4;
    const int wr = (w >> 1) * 64, wc = (w & 1) * 64;

    const u16 *pAh[2], *pAl[2];
#pragma unroll
    for (int j = 0; j < 2; ++j) {
        const int ra = i0 + (w * 2 + j) * 16 + (lane >> 2);
        const int cb = (lane & 3) * 8;
        pAh[j] = Ah + (size_t)ra * 256 + cb;
        pAl[j] = Al + (size_t)ra * 256 + cb;
    }

    f4v acc[4][4] = {};

    for (int kt = 0; kt < 8; ++kt) {
        // stage A hi/lo via global_load_lds (linear 1KB chunks)
#pragma unroll
        for (int j = 0; j < 2; ++j) {
            glds16(pAh[j] + kt * 32, sAh + (w * 2 + j) * 512);
            glds16(pAl[j] + kt * 32, sAl + (w * 2 + j) * 512);
        }
        // stage B: load fp32, split to hi/lo, ds_write
#pragma unroll
        for (int i = 0; i < 4; ++i) {
            const int cc  = tid + i * 256;
            const int row = cc >> 3;
            const int col = (cc & 7) * 4;
            const float* src = Bf + (size_t)(r0 + row) * 256 + kt * 32 + col;
            float4 x = *(const float4*)src;
            u16x4 hh, ll; u16 a, b;
            split2f(x.x, a, b); hh[0] = a; ll[0] = b;
            split2f(x.y, a, b); hh[1] = a; ll[1] = b;
            split2f(x.z, a, b); hh[2] = a; ll[2] = b;
            split2f(x.w, a, b); hh[3] = a; ll[3] = b;
            *(u16x4*)(sBh + row * 32 + col) = hh;
            *(u16x4*)(sBl + row * 32 + col) = ll;
        }
        __syncthreads();

        s8v fah[4], fal[4], fbh[4], fbl[4];
#pragma unroll
        for (int m = 0; m < 4; ++m) {
            fah[m] = *(const s8v*)(sAh + (wr + m * 16 + lr) * 32 + lk * 8);
            fal[m] = *(const s8v*)(sAl + (wr + m * 16 + lr) * 32 + lk * 8);
            fbh[m] = *(const s8v*)(sBh + (wc + m * 16 + lr) * 32 + lk * 8);
            fbl[m] = *(const s8v*)(sBl + (wc + m * 16 + lr) * 32 + lk * 8);
        }
#pragma unroll
        for (int m = 0; m < 4; ++m)
#pragma unroll
            for (int n = 0; n < 4; ++n)
                acc[m][n] = MFMA(fah[m], fbh[n], acc[m][n]);
#pragma unroll
        for (int m = 0; m < 4; ++m)
#pragma unroll
            for (int n = 0; n < 4; ++n)
                acc[m][n] = MFMA(fah[m], fbl[n], acc[m][n]);
#pragma unroll
        for (int m = 0; m < 4; ++m)
#pragma unroll
            for (int n = 0; n < 4; ++n)
                acc[m][n] = MFMA(fal[m], fbh[n], acc[m][n]);
        __syncthreads();
    }

    // epilogue: +bias, split, store transposed output [hid'][32768]
#pragma unroll
    for (int m = 0; m < 4; ++m) {
#pragma unroll
        for (int q = 0; q < 4; ++q) {
            const int rowg = i0 + wr + m * 16 + lk * 4 + q;
            const float bv = bias[rowg];
#pragma unroll
            for (int n = 0; n < 4; ++n) {
                const int colg = r0 + wc + n * 16 + lr;
                float v = acc[m][n][q] + bv;
                u16 hi, lo; split2f(v, hi, lo);
                const size_t off = (size_t)rowg * R_TOT + colg;
                Oh[off] = hi; Ol[off] = lo;
            }
        }
    }
}

// ---------------- big GEMM: H[b][i=n][j=h] = relu( sum_m G[i][m] * Tt[j][b*4096+m] ) ----------------
// A = G pre-split [4096][4096]; B = Tt pre-split [256][32768]. Output fp32 [32768][256].
__global__ __launch_bounds__(256, 2) void gemm_big_k(
    const u16* __restrict__ Gh, const u16* __restrict__ Gl,
    const u16* __restrict__ Th, const u16* __restrict__ Tl,
    float* __restrict__ Hout)
{
    __shared__ u16 sAh[4096], sAl[4096], sBh[4096], sBl[4096];  // 128x32 each
    const int tid = threadIdx.x;
    const int w = tid >> 6, lane = tid & 63;
    const int n0 = blockIdx.x * 128;
    const int h0 = blockIdx.y * 128;
    const int b  = blockIdx.z;
    const int lr = lane & 15, lk = lane >> 4;
    const int wr = (w >> 1) * 64, wc = (w & 1) * 64;

    const u16 *pAh[2], *pAl[2], *pBh[2], *pBl[2];
#pragma unroll
    for (int j = 0; j < 2; ++j) {
        const int cb = (lane & 3) * 8;
        const int ra = n0 + (w * 2 + j) * 16 + (lane >> 2);
        pAh[j] = Gh + (size_t)ra * 4096 + cb;
        pAl[j] = Gl + (size_t)ra * 4096 + cb;
        const int rb = h0 + (w * 2 + j) * 16 + (lane >> 2);
        pBh[j] = Th + (size_t)rb * R_TOT + (size_t)b * 4096 + cb;
        pBl[j] = Tl + (size_t)rb * R_TOT + (size_t)b * 4096 + cb;
    }

    f4v acc[4][4] = {};

    for (int kt = 0; kt < 128; ++kt) {
#pragma unroll
        for (int j = 0; j < 2; ++j) {
            glds16(pAh[j], sAh + (w * 2 + j) * 512);
            glds16(pAl[j], sAl + (w * 2 + j) * 512);
            glds16(pBh[j], sBh + (w * 2 + j) * 512);
            glds16(pBl[j], sBl + (w * 2 + j) * 512);
        }
        __syncthreads();

        s8v fah[4], fal[4], fbh[4], fbl[4];
#pragma unroll
        for (int m = 0; m < 4; ++m) {
            fah[m] = *(const s8v*)(sAh + (wr + m * 16 + lr) * 32 + lk * 8);
            fal[m] = *(const s8v*)(sAl + (wr + m * 16 + lr) * 32 + lk * 8);
            fbh[m] = *(const s8v*)(sBh + (wc + m * 16 + lr) * 32 + lk * 8);
            fbl[m] = *(const s8v*)(sBl + (wc + m * 16 + lr) * 32 + lk * 8);
        }
#pragma unroll
        for (int m = 0; m < 4; ++m)
#pragma unroll
            for (int n = 0; n < 4; ++n)
                acc[m][n] = MFMA(fah[m], fbh[n], acc[m][n]);
#pragma unroll
        for (int m = 0; m < 4; ++m)
#pragma unroll
            for (int n = 0; n < 4; ++n)
                acc[m][n] = MFMA(fah[m], fbl[n], acc[m][n]);
#pragma unroll
        for (int m = 0; m < 4; ++m)
#pragma unroll
            for (int n = 0; n < 4; ++n)
                acc[m][n] = MFMA(fal[m], fbh[n], acc[m][n]);
        __syncthreads();
#pragma unroll
        for (int j = 0; j < 2; ++j) { pAh[j] += 32; pAl[j] += 32; pBh[j] += 32; pBl[j] += 32; }
    }

    // epilogue: relu, store fp32 H[b*4096+row][col]
    float* out = Hout + ((size_t)b * 4096 + n0 + wr + lk * 4) * 256 + h0 + wc + lr;
#pragma unroll
    for (int m = 0; m < 4; ++m)
#pragma unroll
        for (int n = 0; n < 4; ++n)
#pragma unroll
            for (int q = 0; q < 4; ++q) {
                float v = acc[m][n][q];
                v = v > 0.f ? v : 0.f;
                out[(size_t)(m * 16 + q) * 256 + n * 16] = v;
            }
}

// ---------------- final MLP: out[r] = relu(H[r,:] @ Wm1 + bm1) @ Wm2 + bm2 ----------------
__global__ __launch_bounds__(256) void mlp_k(
    const float* __restrict__ H, const float* __restrict__ Wm1,
    const float* __restrict__ bm1, const float* __restrict__ Wm2,
    const float* __restrict__ bm2, float* __restrict__ out)
{
    __shared__ float rb[4][256];
    const int w = threadIdx.x >> 6, lane = threadIdx.x & 63;
    const int gw0 = blockIdx.x * 4 + w;
    const int stride = gridDim.x * 4;
    for (int r = gw0; r < R_TOT; r += stride) {
        float4 v = *(const float4*)(H + (size_t)r * 256 + lane * 4);
        *(float4*)&rb[w][lane * 4] = v;
        __syncthreads();
        float acc = 0.f;
#pragma unroll 8
        for (int k = 0; k < 256; ++k)
            acc = fmaf(rb[w][k], Wm1[k * 64 + lane], acc);
        float m = acc + bm1[lane];
        m = m > 0.f ? m : 0.f;
        float s = m * Wm2[lane];
#pragma unroll
        for (int off = 32; off; off >>= 1) s += __shfl_down(s, off);
        if (lane == 0) out[r] = s + bm2[0];
        __syncthreads();
    }
}

// ---------------- launch ----------------
extern "C" void kernel_launch(void* const* d_in, const int* in_sizes, int n_in,
                              void* d_out, int out_size, void* d_ws, size_t ws_size,
                              hipStream_t stream) {
    (void)in_sizes; (void)n_in; (void)out_size; (void)ws_size;
    const float* X   = (const float*)d_in[0];
    const float* G   = (const float*)d_in[1];
    const float* W1  = (const float*)d_in[2];
    const float* b1  = (const float*)d_in[3];
    const float* W2  = (const float*)d_in[4];
    const float* b2  = (const float*)d_in[5];
    const float* Wm1 = (const float*)d_in[6];
    const float* bm1 = (const float*)d_in[7];
    const float* Wm2 = (const float*)d_in[8];
    const float* bm2 = (const float*)d_in[9];
    float* out = (float*)d_out;

    char* ws = (char*)d_ws;
    u16* Gh   = (u16*)(ws);                     // 33554432 B
    u16* Gl   = (u16*)(ws + 33554432u);         // 33554432 B
    u16* W1th = (u16*)(ws + 67108864u);         // 131072 B
    u16* W1tl = (u16*)(ws + 67239936u);
    u16* W2th = (u16*)(ws + 67371008u);
    u16* W2tl = (u16*)(ws + 67502080u);
    u16* Tth  = (u16*)(ws + 67633152u);         // 16777216 B
    u16* Ttl  = (u16*)(ws + 84410368u);         // 16777216 B
    float* Hb = (float*)(ws + 101187584u);      // 33554432 B  (total 134742016 B)

    splitK_k<<<2048, 256, 0, stream>>>(G, Gh, Gl, 16777216 / 4);
    splitT_k<<<256, 256, 0, stream>>>(W1, W1th, W1tl);
    splitT_k<<<256, 256, 0, stream>>>(W2, W2th, W2tl);

    // conv1 pre-prop: T1t = (X @ W1 + b1)^T, split
    gemm_small_k<<<dim3(2, 256), 256, 0, stream>>>(W1th, W1tl, X, b1, Tth, Ttl);
    // conv1 prop: H1 = relu(G @ T1)
    gemm_big_k<<<dim3(32, 2, 8), 256, 0, stream>>>(Gh, Gl, Tth, Ttl, Hb);
    // conv2 pre-prop: T2t = (H1 @ W2 + b2)^T, split
    gemm_small_k<<<dim3(2, 256), 256, 0, stream>>>(W2th, W2tl, Hb, b2, Tth, Ttl);
    // conv2 prop: H2 = relu(G @ T2)
    gemm_big_k<<<dim3(32, 2, 8), 256, 0, stream>>>(Gh, Gl, Tth, Ttl, Hb);
    // final MLP
    mlp_k<<<2048, 256, 0, stream>>>(Hb, Wm1, bm1, Wm2, bm2, out);
}

// Round 2
// 490.536 us; speedup vs baseline: 1.0106x; 1.0106x over previous
//
#include <hip/hip_runtime.h>

// Problem constants
#define N_NODES 4096
#define C_IN    256
#define HID     256
#define BATCH   8
#define R_TOT   32768   // BATCH * N_NODES

typedef unsigned short u16;
typedef short s8v  __attribute__((ext_vector_type(8)));   // 8 bf16 (bit pattern in shorts)
typedef float f4v  __attribute__((ext_vector_type(4)));
typedef u16   u16x4 __attribute__((ext_vector_type(4)));

#define MFMA(a,b,c) __builtin_amdgcn_mfma_f32_16x16x32_bf16((a),(b),(c),0,0,0)

__device__ __forceinline__ u16 bf_rne(float x) {
    unsigned u = __float_as_uint(x);
    u += 0x7fffu + ((u >> 16) & 1u);
    return (u16)(u >> 16);
}
__device__ __forceinline__ float bf_f(u16 h) {
    return __uint_as_float(((unsigned)h) << 16);
}
// fp32 -> bf16 hi/lo split: x ~= hi + lo, |err| <= 2^-18 |x|
__device__ __forceinline__ void split2f(float x, u16& h, u16& l) {
    h = bf_rne(x);
    l = bf_rne(x - bf_f(h));
}

// async global->LDS, 16B per lane. lds ptr must be wave-uniform (dest = base + lane*16)
__device__ __forceinline__ void glds16(const void* g, void* l) {
    __builtin_amdgcn_global_load_lds(
        (const __attribute__((address_space(1))) void*)g,
        (__attribute__((address_space(3))) void*)l, 16, 0, 0);
}

// ---------------- split kernels ----------------

// elementwise fp32 -> (hi,lo) bf16, float4-vectorized
__global__ void splitK_k(const float* __restrict__ in, u16* __restrict__ oh,
                         u16* __restrict__ ol, int n4) {
    int i = blockIdx.x * blockDim.x + threadIdx.x;
    int stride = gridDim.x * blockDim.x;
    for (; i < n4; i += stride) {
        float4 x = ((const float4*)in)[i];
        u16x4 hh, ll; u16 a, b;
        split2f(x.x, a, b); hh[0] = a; ll[0] = b;
        split2f(x.y, a, b); hh[1] = a; ll[1] = b;
        split2f(x.z, a, b); hh[2] = a; ll[2] = b;
        split2f(x.w, a, b); hh[3] = a; ll[3] = b;
        ((u16x4*)oh)[i] = hh; ((u16x4*)ol)[i] = ll;
    }
}

// transpose + split for the 256x256 weight matrices: out[h][c] = in[c][h]
__global__ void splitT_k(const float* __restrict__ in, u16* __restrict__ oh,
                         u16* __restrict__ ol) {
    int c = blockIdx.x;      // row of in
    int h = threadIdx.x;     // col of in
    float v = in[c * 256 + h];
    u16 hi, lo; split2f(v, hi, lo);
    oh[h * 256 + c] = hi;
    ol[h * 256 + c] = lo;
}

// ---------------- small GEMM: T[i=hid'][j=r] = sum_k Wt[i][k] * Bf[j][k] + bias[i] ----------------
// A (Wt) pre-split bf16 [256][256]; B fp32 [32768][256] reg-staged+split on the fly.
// Output written split hi/lo, transposed layout [256][32768]. No relu.
// LDS tiles use the (row>>1)&3 16B-slot XOR swizzle; A staged via pre-swizzled
// global source (global_load_lds writes linearly), B swizzled at ds_write.
__global__ __launch_bounds__(256, 2) void gemm_small_k(
    const u16* __restrict__ Ah, const u16* __restrict__ Al,
    const float* __restrict__ Bf, const float* __restrict__ bias,
    u16* __restrict__ Oh, u16* __restrict__ Ol)
{
    __shared__ u16 sAh[4096], sAl[4096], sBh[4096], sBl[4096];  // 128x32 each
    const int tid = threadIdx.x;
    const int w = tid >> 6, lane = tid & 63;
    const int i0 = blockIdx.x * 128;   // output row tile (hid')
    const int r0 = blockIdx.y * 128;   // output col tile (r)
    const int lr = lane & 15, lk = lane >> 4;
    const int wr = (w >> 1) * 64, wc = (w & 1) * 64;
    const int kslot = (lk ^ ((lr >> 1) & 3)) * 8;   // swizzled read slot (u16 units)

    const u16 *pAh[2], *pAl[2];
    const int cb = ((lane & 3) ^ ((lane >> 3) & 3)) * 8;  // pre-swizzled source slot
#pragma unroll
    for (int j = 0; j < 2; ++j) {
        const int ra = i0 + (w * 2 + j) * 16 + (lane >> 2);
        pAh[j] = Ah + (size_t)ra * 256 + cb;
        pAl[j] = Al + (size_t)ra * 256 + cb;
    }

    f4v acc[4][4] = {};

    for (int kt = 0; kt < 8; ++kt) {
        // stage A hi/lo via global_load_lds (linear 1KB chunks, source pre-swizzled)
#pragma unroll
        for (int j = 0; j < 2; ++j) {
            glds16(pAh[j] + kt * 32, sAh + (w * 2 + j) * 512);
            glds16(pAl[j] + kt * 32, sAl + (w * 2 + j) * 512);
        }
        // stage B: load fp32, split to hi/lo, ds_write at swizzled slot
#pragma unroll
        for (int i = 0; i < 4; ++i) {
            const int cc  = tid + i * 256;
            const int row = cc >> 3;
            const int col = (((((cc & 7) >> 1) ^ ((cc >> 4) & 3)) << 3)) | ((cc & 1) * 4);
            const float* src = Bf + (size_t)(r0 + row) * 256 + kt * 32 + (cc & 7) * 4;
            float4 x = *(const float4*)src;
            u16x4 hh, ll; u16 a, b;
            split2f(x.x, a, b); hh[0] = a; ll[0] = b;
            split2f(x.y, a, b); hh[1] = a; ll[1] = b;
            split2f(x.z, a, b); hh[2] = a; ll[2] = b;
            split2f(x.w, a, b); hh[3] = a; ll[3] = b;
            *(u16x4*)(sBh + row * 32 + col) = hh;
            *(u16x4*)(sBl + row * 32 + col) = ll;
        }
        __syncthreads();

        s8v fah[4], fal[4], fbh[4], fbl[4];
#pragma unroll
        for (int m = 0; m < 4; ++m) {
            fah[m] = *(const s8v*)(sAh + (wr + m * 16 + lr) * 32 + kslot);
            fal[m] = *(const s8v*)(sAl + (wr + m * 16 + lr) * 32 + kslot);
            fbh[m] = *(const s8v*)(sBh + (wc + m * 16 + lr) * 32 + kslot);
            fbl[m] = *(const s8v*)(sBl + (wc + m * 16 + lr) * 32 + kslot);
        }
#pragma unroll
        for (int m = 0; m < 4; ++m)
#pragma unroll
            for (int n = 0; n < 4; ++n)
                acc[m][n] = MFMA(fah[m], fbh[n], acc[m][n]);
#pragma unroll
        for (int m = 0; m < 4; ++m)
#pragma unroll
            for (int n = 0; n < 4; ++n)
                acc[m][n] = MFMA(fah[m], fbl[n], acc[m][n]);
#pragma unroll
        for (int m = 0; m < 4; ++m)
#pragma unroll
            for (int n = 0; n < 4; ++n)
                acc[m][n] = MFMA(fal[m], fbh[n], acc[m][n]);
        __syncthreads();
    }

    // epilogue: +bias, split, store transposed output [hid'][32768]
#pragma unroll
    for (int m = 0; m < 4; ++m) {
#pragma unroll
        for (int q = 0; q < 4; ++q) {
            const int rowg = i0 + wr + m * 16 + lk * 4 + q;
            const float bv = bias[rowg];
#pragma unroll
            for (int n = 0; n < 4; ++n) {
                const int colg = r0 + wc + n * 16 + lr;
                float v = acc[m][n][q] + bv;
                u16 hi, lo; split2f(v, hi, lo);
                const size_t off = (size_t)rowg * R_TOT + colg;
                Oh[off] = hi; Ol[off] = lo;
            }
        }
    }
}

// ---------------- big GEMM: H[b][i=n][j=h] = relu( sum_m G[i][m] * Tt[j][b*4096+m] ) ----------------
// A = G pre-split [4096][4096]; B = Tt pre-split [256][32768]. Output fp32 [32768][256].
// Double-buffered LDS (stage kt+1 before compute kt) + swizzled tiles.
__global__ __launch_bounds__(256, 2) void gemm_big_k(
    const u16* __restrict__ Gh, const u16* __restrict__ Gl,
    const u16* __restrict__ Th, const u16* __restrict__ Tl,
    float* __restrict__ Hout)
{
    __shared__ u16 lds[2][4][4096];   // [buf][Ah,Al,Bh,Bl][128x32], 64 KB
    const int tid = threadIdx.x;
    const int w = tid >> 6, lane = tid & 63;
    const int n0 = blockIdx.x * 128;
    const int h0 = blockIdx.y * 128;
    const int b  = blockIdx.z;
    const int lr = lane & 15, lk = lane >> 4;
    const int wr = (w >> 1) * 64, wc = (w & 1) * 64;
    const int kslot = (lk ^ ((lr >> 1) & 3)) * 8;   // swizzled read slot (u16 units)

    const u16 *pAh[2], *pAl[2], *pBh[2], *pBl[2];
    const int cb = ((lane & 3) ^ ((lane >> 3) & 3)) * 8;  // pre-swizzled source slot
#pragma unroll
    for (int j = 0; j < 2; ++j) {
        const int ra = n0 + (w * 2 + j) * 16 + (lane >> 2);
        pAh[j] = Gh + (size_t)ra * 4096 + cb;
        pAl[j] = Gl + (size_t)ra * 4096 + cb;
        const int rb = h0 + (w * 2 + j) * 16 + (lane >> 2);
        pBh[j] = Th + (size_t)rb * R_TOT + (size_t)b * 4096 + cb;
        pBl[j] = Tl + (size_t)rb * R_TOT + (size_t)b * 4096 + cb;
    }

    f4v acc[4][4] = {};

#define STAGE(BUF) do {                                                        \
    _Pragma("unroll")                                                          \
    for (int j = 0; j < 2; ++j) {                                              \
        glds16(pAh[j], &lds[BUF][0][(w * 2 + j) * 512]);                       \
        glds16(pAl[j], &lds[BUF][1][(w * 2 + j) * 512]);                       \
        glds16(pBh[j], &lds[BUF][2][(w * 2 + j) * 512]);                       \
        glds16(pBl[j], &lds[BUF][3][(w * 2 + j) * 512]);                       \
    }                                                                          \
    _Pragma("unroll")                                                          \
    for (int j = 0; j < 2; ++j) {                                              \
        pAh[j] += 32; pAl[j] += 32; pBh[j] += 32; pBl[j] += 32;                \
    }                                                                          \
} while (0)

#define COMPUTE(BUF) do {                                                      \
    s8v fah[4], fal[4], fbh[4], fbl[4];                                        \
    _Pragma("unroll")                                                          \
    for (int m = 0; m < 4; ++m) {                                              \
        fah[m] = *(const s8v*)(&lds[BUF][0][(wr + m * 16 + lr) * 32 + kslot]); \
        fal[m] = *(const s8v*)(&lds[BUF][1][(wr + m * 16 + lr) * 32 + kslot]); \
        fbh[m] = *(const s8v*)(&lds[BUF][2][(wc + m * 16 + lr) * 32 + kslot]); \
        fbl[m] = *(const s8v*)(&lds[BUF][3][(wc + m * 16 + lr) * 32 + kslot]); \
    }                                                                          \
    _Pragma("unroll")                                                          \
    for (int m = 0; m < 4; ++m)                                                \
        _Pragma("unroll")                                                      \
        for (int n = 0; n < 4; ++n)                                            \
            acc[m][n] = MFMA(fah[m], fbh[n], acc[m][n]);                       \
    _Pragma("unroll")                                                          \
    for (int m = 0; m < 4; ++m)                                                \
        _Pragma("unroll")                                                      \
        for (int n = 0; n < 4; ++n)                                            \
            acc[m][n] = MFMA(fah[m], fbl[n], acc[m][n]);                       \
    _Pragma("unroll")                                                          \
    for (int m = 0; m < 4; ++m)                                                \
        _Pragma("unroll")                                                      \
        for (int n = 0; n < 4; ++n)                                            \
            acc[m][n] = MFMA(fal[m], fbh[n], acc[m][n]);                       \
} while (0)

    STAGE(0);                 // kt = 0
    __syncthreads();
    for (int kt = 0; kt < 128; kt += 2) {
        STAGE(1);             // stage kt+1 while computing kt
        COMPUTE(0);
        __syncthreads();      // drain: staged loads had ds_read+MFMA time in flight
        if (kt + 2 < 128) STAGE(0);
        COMPUTE(1);
        __syncthreads();
    }
#undef STAGE
#undef COMPUTE

    // epilogue: relu, store fp32 H[b*4096+row][col]
    float* out = Hout + ((size_t)b * 4096 + n0 + wr + lk * 4) * 256 + h0 + wc + lr;
#pragma unroll
    for (int m = 0; m < 4; ++m)
#pragma unroll
        for (int n = 0; n < 4; ++n)
#pragma unroll
            for (int q = 0; q < 4; ++q) {
                float v = acc[m][n][q];
                v = v > 0.f ? v : 0.f;
                out[(size_t)(m * 16 + q) * 256 + n * 16] = v;
            }
}

// ---------------- final MLP: out[r] = relu(H[r,:] @ Wm1 + bm1) @ Wm2 + bm2 ----------------
__global__ __launch_bounds__(256) void mlp_k(
    const float* __restrict__ H, const float* __restrict__ Wm1,
    const float* __restrict__ bm1, const float* __restrict__ Wm2,
    const float* __restrict__ bm2, float* __restrict__ out)
{
    __shared__ float rb[4][256];
    const int w = threadIdx.x >> 6, lane = threadIdx.x & 63;
    const int gw0 = blockIdx.x * 4 + w;
    const int stride = gridDim.x * 4;
    for (int r = gw0; r < R_TOT; r += stride) {
        float4 v = *(const float4*)(H + (size_t)r * 256 + lane * 4);
        *(float4*)&rb[w][lane * 4] = v;
        __syncthreads();
        float acc = 0.f;
#pragma unroll 8
        for (int k = 0; k < 256; ++k)
            acc = fmaf(rb[w][k], Wm1[k * 64 + lane], acc);
        float m = acc + bm1[lane];
        m = m > 0.f ? m : 0.f;
        float s = m * Wm2[lane];
#pragma unroll
        for (int off = 32; off; off >>= 1) s += __shfl_down(s, off);
        if (lane == 0) out[r] = s + bm2[0];
        __syncthreads();
    }
}

// ---------------- launch ----------------
extern "C" void kernel_launch(void* const* d_in, const int* in_sizes, int n_in,
                              void* d_out, int out_size, void* d_ws, size_t ws_size,
                              hipStream_t stream) {
    (void)in_sizes; (void)n_in; (void)out_size; (void)ws_size;
    const float* X   = (const float*)d_in[0];
    const float* G   = (const float*)d_in[1];
    const float* W1  = (const float*)d_in[2];
    const float* b1  = (const float*)d_in[3];
    const float* W2  = (const float*)d_in[4];
    const float* b2  = (const float*)d_in[5];
    const float* Wm1 = (const float*)d_in[6];
    const float* bm1 = (const float*)d_in[7];
    const float* Wm2 = (const float*)d_in[8];
    const float* bm2 = (const float*)d_in[9];
    float* out = (float*)d_out;

    char* ws = (char*)d_ws;
    u16* Gh   = (u16*)(ws);                     // 33554432 B
    u16* Gl   = (u16*)(ws + 33554432u);         // 33554432 B
    u16* W1th = (u16*)(ws + 67108864u);         // 131072 B
    u16* W1tl = (u16*)(ws + 67239936u);
    u16* W2th = (u16*)(ws + 67371008u);
    u16* W2tl = (u16*)(ws + 67502080u);
    u16* Tth  = (u16*)(ws + 67633152u);         // 16777216 B
    u16* Ttl  = (u16*)(ws + 84410368u);         // 16777216 B
    float* Hb = (float*)(ws + 101187584u);      // 33554432 B  (total 134742016 B)

    splitK_k<<<2048, 256, 0, stream>>>(G, Gh, Gl, 16777216 / 4);
    splitT_k<<<256, 256, 0, stream>>>(W1, W1th, W1tl);
    splitT_k<<<256, 256, 0, stream>>>(W2, W2th, W2tl);

    // conv1 pre-prop: T1t = (X @ W1 + b1)^T, split
    gemm_small_k<<<dim3(2, 256), 256, 0, stream>>>(W1th, W1tl, X, b1, Tth, Ttl);
    // conv1 prop: H1 = relu(G @ T1)
    gemm_big_k<<<dim3(32, 2, 8), 256, 0, stream>>>(Gh, Gl, Tth, Ttl, Hb);
    // conv2 pre-prop: T2t = (H1 @ W2 + b2)^T, split
    gemm_small_k<<<dim3(2, 256), 256, 0, stream>>>(W2th, W2tl, Hb, b2, Tth, Ttl);
    // conv2 prop: H2 = relu(G @ T2)
    gemm_big_k<<<dim3(32, 2, 8), 256, 0, stream>>>(Gh, Gl, Tth, Ttl, Hb);
    // final MLP
    mlp_k<<<2048, 256, 0, stream>>>(Hb, Wm1, bm1, Wm2, bm2, out);
}